// Round 1
// baseline (975.632 us; speedup 1.0000x reference)
//
#include <hip/hip_runtime.h>
#include <hip/hip_bf16.h>

#define T_TOK 1024
#define NEXP 16
#define HD 2048
#define TOPK 6

typedef __attribute__((ext_vector_type(8))) short short8;
typedef __attribute__((ext_vector_type(4))) float floatx4;

__device__ __forceinline__ short f2bf(float f) {
    unsigned u = __builtin_bit_cast(unsigned, f);
    u += 0x7FFFu + ((u >> 16) & 1u);
    return (short)(u >> 16);
}

__device__ __forceinline__ short8 pack8(const float4 p, const float4 q) {
    short8 v;
    v[0] = f2bf(p.x); v[1] = f2bf(p.y); v[2] = f2bf(p.z); v[3] = f2bf(p.w);
    v[4] = f2bf(q.x); v[5] = f2bf(q.y); v[6] = f2bf(q.z); v[7] = f2bf(q.w);
    return v;
}

// ---------------- router: logits (fp32) -> sigmoid -> top6 -> expert lists ----
__global__ __launch_bounds__(64) void router_kernel(
    const float* __restrict__ X, const float* __restrict__ GW,
    const float* __restrict__ bias, int* __restrict__ counts,
    int* __restrict__ lists, float* __restrict__ wgts)
{
    const int t = blockIdx.x;
    const int l = threadIdx.x;
    const float* x = X + (size_t)t * HD;
    float acc[NEXP];
#pragma unroll
    for (int e = 0; e < NEXP; ++e) acc[e] = 0.f;
    for (int k = l; k < HD; k += 64) {
        const float xv = x[k];
#pragma unroll
        for (int e = 0; e < NEXP; ++e) acc[e] += xv * GW[e * HD + k];
    }
#pragma unroll
    for (int e = 0; e < NEXP; ++e) {
        float v = acc[e];
#pragma unroll
        for (int m = 32; m >= 1; m >>= 1) v += __shfl_xor(v, m, 64);
        acc[e] = v;
    }
    if (l == 0) {
        float s[NEXP], choice[NEXP];
#pragma unroll
        for (int e = 0; e < NEXP; ++e) {
            s[e] = 1.f / (1.f + __expf(-acc[e]));
            choice[e] = s[e] + bias[e];
        }
        int idx[TOPK]; float wv[TOPK]; float wsum = 0.f;
        bool used[NEXP];
#pragma unroll
        for (int e = 0; e < NEXP; ++e) used[e] = false;
        for (int j = 0; j < TOPK; ++j) {
            float best = -1e30f; int bi = 0;
            for (int e = 0; e < NEXP; ++e)
                if (!used[e] && choice[e] > best) { best = choice[e]; bi = e; }
            used[bi] = true; idx[j] = bi; wv[j] = s[bi]; wsum += s[bi];
        }
        const float scale = 2.5f / wsum;
        for (int j = 0; j < TOPK; ++j) {
            const int e = idx[j];
            const int pos = atomicAdd(&counts[e], 1);
            lists[e * T_TOK + pos] = t;
            wgts[e * T_TOK + pos] = wv[j] * scale;
        }
    }
}

__global__ void offsets_kernel(const int* __restrict__ counts, int* __restrict__ offs)
{
    if (threadIdx.x == 0 && blockIdx.x == 0) {
        int a = 0;
        for (int e = 0; e < NEXP; ++e) { offs[e] = a; a += counts[e]; }
    }
}

// ---------------- gate_up GEMM + fused silu*mul -----------------------------
// Tile: 128 tokens x (64 gate rows + 64 up rows), BK=32, 4 waves (2x2).
// Wave (wx,wy): rows wy*64..+64, gate cols wx*32..+32 and matching up cols.
// Frag cb in {0,1}=gate, {2,3}=up -> silu(acc[mc][cb])*acc[mc][cb+2] in-register.
__global__ __launch_bounds__(256) void gateup_kernel(
    const float* __restrict__ X, const float* __restrict__ W,
    const int* __restrict__ counts, const int* __restrict__ offs,
    const int* __restrict__ lists, short* __restrict__ Hout,
    int K, int Ih, int denseCount)
{
    __shared__ short sA[128][40];   // stride 40 shorts = 80B: frag reads 2-way only
    __shared__ short sB[128][40];
    const int e = blockIdx.z;
    const int cnt = counts ? counts[e] : denseCount;
    const int m0 = blockIdx.y * 128;
    if (m0 >= cnt) return;
    const int i0 = blockIdx.x * 64;
    const float* We = W + (size_t)e * (size_t)(2 * Ih) * K;
    const int hbase = offs ? offs[e] : 0;

    const int tid = threadIdx.x;
    const int lrow = tid >> 1;          // 0..127
    const int kc = (tid & 1) * 16;      // 0 or 16

    int am = m0 + lrow; if (am > cnt - 1) am = cnt - 1;
    const int tok = lists ? lists[e * T_TOK + am] : am;
    const float* aptr = X + (size_t)tok * K + kc;
    const int brow = (lrow < 64) ? (i0 + lrow) : (Ih + i0 + (lrow - 64));
    const float* bptr = We + (size_t)brow * K + kc;

    const int wave = tid >> 6, lane = tid & 63;
    const int wx = wave & 1, wy = wave >> 1;
    const int l15 = lane & 15, l4 = lane >> 4;

    floatx4 acc[4][4];
#pragma unroll
    for (int a = 0; a < 4; ++a)
#pragma unroll
        for (int b = 0; b < 4; ++b) acc[a][b] = (floatx4){0.f, 0.f, 0.f, 0.f};

    for (int k0 = 0; k0 < K; k0 += 32) {
        const float4 a0 = *(const float4*)(aptr + k0);
        const float4 a1 = *(const float4*)(aptr + k0 + 4);
        const float4 a2 = *(const float4*)(aptr + k0 + 8);
        const float4 a3 = *(const float4*)(aptr + k0 + 12);
        const float4 b0 = *(const float4*)(bptr + k0);
        const float4 b1 = *(const float4*)(bptr + k0 + 4);
        const float4 b2 = *(const float4*)(bptr + k0 + 8);
        const float4 b3 = *(const float4*)(bptr + k0 + 12);
        *(short8*)&sA[lrow][kc]     = pack8(a0, a1);
        *(short8*)&sA[lrow][kc + 8] = pack8(a2, a3);
        *(short8*)&sB[lrow][kc]     = pack8(b0, b1);
        *(short8*)&sB[lrow][kc + 8] = pack8(b2, b3);
        __syncthreads();
        short8 af[4], bfr[4];
#pragma unroll
        for (int mc = 0; mc < 4; ++mc)
            af[mc] = *(const short8*)&sA[wy * 64 + mc * 16 + l15][l4 * 8];
#pragma unroll
        for (int cb = 0; cb < 4; ++cb) {
            const int br = ((cb < 2) ? 0 : 64) + wx * 32 + (cb & 1) * 16 + l15;
            bfr[cb] = *(const short8*)&sB[br][l4 * 8];
        }
#pragma unroll
        for (int mc = 0; mc < 4; ++mc)
#pragma unroll
            for (int cb = 0; cb < 4; ++cb)
                acc[mc][cb] = __builtin_amdgcn_mfma_f32_16x16x32_bf16(
                    af[mc], bfr[cb], acc[mc][cb], 0, 0, 0);
        __syncthreads();
    }

#pragma unroll
    for (int mc = 0; mc < 4; ++mc)
#pragma unroll
        for (int cb = 0; cb < 2; ++cb)
#pragma unroll
            for (int r = 0; r < 4; ++r) {
                const int mrel = wy * 64 + mc * 16 + l4 * 4 + r;
                if (m0 + mrel < cnt) {
                    const float g = acc[mc][cb][r];
                    const float u = acc[mc][cb + 2][r];
                    const float h = g / (1.f + __expf(-g)) * u;
                    const int col = i0 + wx * 32 + cb * 16 + l15;
                    Hout[(size_t)(hbase + m0 + mrel) * Ih + col] = f2bf(h);
                }
            }
}

// ---------------- down GEMM: plain store (shared) or weighted atomic scatter -
__global__ __launch_bounds__(256) void down_kernel(
    const short* __restrict__ Hin, const float* __restrict__ W2,
    const int* __restrict__ counts, const int* __restrict__ offs,
    const int* __restrict__ lists, const float* __restrict__ wgts,
    float* __restrict__ out, int Kih, int Ho, int denseCount)
{
    __shared__ short sA[128][40];
    __shared__ short sB[128][40];
    const int e = blockIdx.z;
    const int cnt = counts ? counts[e] : denseCount;
    const int m0 = blockIdx.y * 128;
    if (m0 >= cnt) return;
    const int n0 = blockIdx.x * 128;
    const float* W2e = W2 + (size_t)e * (size_t)Ho * Kih;
    const int hbase = offs ? offs[e] : 0;

    const int tid = threadIdx.x;
    const int lrow = tid >> 1;
    const int kc = (tid & 1) * 16;

    int am = m0 + lrow; if (am > cnt - 1) am = cnt - 1;
    const short* aptr = Hin + (size_t)(hbase + am) * Kih + kc;
    const float* bptr = W2e + (size_t)(n0 + lrow) * Kih + kc;

    const int wave = tid >> 6, lane = tid & 63;
    const int wx = wave & 1, wy = wave >> 1;
    const int l15 = lane & 15, l4 = lane >> 4;

    floatx4 acc[4][4];
#pragma unroll
    for (int a = 0; a < 4; ++a)
#pragma unroll
        for (int b = 0; b < 4; ++b) acc[a][b] = (floatx4){0.f, 0.f, 0.f, 0.f};

    for (int k0 = 0; k0 < Kih; k0 += 32) {
        const short8 ha0 = *(const short8*)(aptr + k0);
        const short8 ha1 = *(const short8*)(aptr + k0 + 8);
        const float4 b0 = *(const float4*)(bptr + k0);
        const float4 b1 = *(const float4*)(bptr + k0 + 4);
        const float4 b2 = *(const float4*)(bptr + k0 + 8);
        const float4 b3 = *(const float4*)(bptr + k0 + 12);
        *(short8*)&sA[lrow][kc]     = ha0;
        *(short8*)&sA[lrow][kc + 8] = ha1;
        *(short8*)&sB[lrow][kc]     = pack8(b0, b1);
        *(short8*)&sB[lrow][kc + 8] = pack8(b2, b3);
        __syncthreads();
        short8 af[4], bfr[4];
#pragma unroll
        for (int mc = 0; mc < 4; ++mc)
            af[mc] = *(const short8*)&sA[wy * 64 + mc * 16 + l15][l4 * 8];
#pragma unroll
        for (int cb = 0; cb < 4; ++cb)
            bfr[cb] = *(const short8*)&sB[wx * 64 + cb * 16 + l15][l4 * 8];
#pragma unroll
        for (int mc = 0; mc < 4; ++mc)
#pragma unroll
            for (int cb = 0; cb < 4; ++cb)
                acc[mc][cb] = __builtin_amdgcn_mfma_f32_16x16x32_bf16(
                    af[mc], bfr[cb], acc[mc][cb], 0, 0, 0);
        __syncthreads();
    }

#pragma unroll
    for (int mc = 0; mc < 4; ++mc)
#pragma unroll
        for (int r = 0; r < 4; ++r) {
            const int mrel = wy * 64 + mc * 16 + l4 * 4 + r;
            if (m0 + mrel >= cnt) continue;
            if (lists) {
                const int t = lists[e * T_TOK + m0 + mrel];
                const float w = wgts[e * T_TOK + m0 + mrel];
                float* orow = out + (size_t)t * Ho + n0 + wx * 64 + l15;
#pragma unroll
                for (int cb = 0; cb < 4; ++cb)
                    atomicAdd(orow + cb * 16, w * acc[mc][cb][r]);
            } else {
                float* orow = out + (size_t)(m0 + mrel) * Ho + n0 + wx * 64 + l15;
#pragma unroll
                for (int cb = 0; cb < 4; ++cb)
                    orow[cb * 16] = acc[mc][cb][r];
            }
        }
}

extern "C" void kernel_launch(void* const* d_in, const int* in_sizes, int n_in,
                              void* d_out, int out_size, void* d_ws, size_t ws_size,
                              hipStream_t stream) {
    const float* X    = (const float*)d_in[0];  // [1024,2048]
    const float* GW   = (const float*)d_in[1];  // [16,2048]
    const float* BIAS = (const float*)d_in[2];  // [16]
    const float* W1   = (const float*)d_in[3];  // [16,2048,2048]
    const float* W2   = (const float*)d_in[4];  // [16,2048,1024]
    const float* SW1  = (const float*)d_in[5];  // [4096,2048]
    const float* SW2  = (const float*)d_in[6];  // [2048,2048]
    float* out = (float*)d_out;                 // [1024,2048] fp32

    // ws layout (~16.9 MB total)
    char* ws = (char*)d_ws;
    int*   counts = (int*)ws;                       // 16
    int*   offs   = counts + 16;                    // 16
    int*   lists  = offs + 16;                      // 16*1024
    float* wgts   = (float*)(lists + 16 * 1024);    // 16*1024
    short* h_r    = (short*)(ws + 135168);                 // 6144*1024 bf16
    short* h_s    = (short*)(ws + 135168 + 12582912);      // 1024*2048 bf16
    const size_t WS_NEEDED = 135168 + 12582912 + 4194304;
    if (ws_size < WS_NEEDED) return;  // visible failure rather than OOB write

    hipMemsetAsync(counts, 0, 16 * sizeof(int), stream);
    router_kernel<<<T_TOK, 64, 0, stream>>>(X, GW, BIAS, counts, lists, wgts);
    offsets_kernel<<<1, 64, 0, stream>>>(counts, offs);

    // shared expert gate_up: K=2048, Ih=Is=2048, dense over all 1024 tokens
    gateup_kernel<<<dim3(32, 8, 1), 256, 0, stream>>>(
        X, SW1, nullptr, nullptr, nullptr, h_s, HD, 2048, T_TOK);
    // routed gate_up: K=2048, Ih=1024, gathered per expert
    gateup_kernel<<<dim3(16, 8, NEXP), 256, 0, stream>>>(
        X, W1, counts, offs, lists, h_r, HD, 1024, 0);

    // shared down: plain stores cover every out element (no memset needed)
    down_kernel<<<dim3(16, 8, 1), 256, 0, stream>>>(
        h_s, SW2, nullptr, nullptr, nullptr, nullptr, out, 2048, HD, T_TOK);
    // routed down: weighted atomic scatter-add on top
    down_kernel<<<dim3(16, 8, NEXP), 256, 0, stream>>>(
        h_r, W2, counts, offs, lists, wgts, out, 1024, HD, 0);
}

// Round 2
// 921.425 us; speedup vs baseline: 1.0588x; 1.0588x over previous
//
#include <hip/hip_runtime.h>
#include <hip/hip_bf16.h>

#define T_TOK 1024
#define NEXP 16
#define HD 2048
#define TOPK 6

typedef __attribute__((ext_vector_type(8))) short short8;
typedef __attribute__((ext_vector_type(4))) float floatx4;

__device__ __forceinline__ short f2bf(float f) {
    unsigned u = __builtin_bit_cast(unsigned, f);
    u += 0x7FFFu + ((u >> 16) & 1u);
    return (short)(u >> 16);
}

__device__ __forceinline__ short8 pack8(const float4 p, const float4 q) {
    short8 v;
    v[0] = f2bf(p.x); v[1] = f2bf(p.y); v[2] = f2bf(p.z); v[3] = f2bf(p.w);
    v[4] = f2bf(q.x); v[5] = f2bf(q.y); v[6] = f2bf(q.z); v[7] = f2bf(q.w);
    return v;
}

typedef __attribute__((address_space(1))) void gvoid;
typedef __attribute__((address_space(3))) void lvoid;
__device__ __forceinline__ void gload_lds16(const void* g, void* l) {
    __builtin_amdgcn_global_load_lds((gvoid*)g, (lvoid*)l, 16, 0, 0);
}

// ---------------- fp32 -> bf16 bulk convert (memory-bound) -------------------
__global__ __launch_bounds__(256) void cvt_kernel(
    const float* __restrict__ s, short* __restrict__ d, int n4)
{
    for (int i = blockIdx.x * blockDim.x + threadIdx.x; i < n4;
         i += gridDim.x * blockDim.x) {
        const float4 v = ((const float4*)s)[i];
        short4 o;
        o.x = f2bf(v.x); o.y = f2bf(v.y); o.z = f2bf(v.z); o.w = f2bf(v.w);
        ((short4*)d)[i] = o;
    }
}

// ---------------- router: logits (fp32) -> sigmoid -> top6 -> expert lists ----
__global__ __launch_bounds__(64) void router_kernel(
    const float* __restrict__ X, const float* __restrict__ GW,
    const float* __restrict__ bias, int* __restrict__ counts,
    int* __restrict__ lists, float* __restrict__ wgts)
{
    const int t = blockIdx.x;
    const int l = threadIdx.x;
    const float* x = X + (size_t)t * HD;
    float acc[NEXP];
#pragma unroll
    for (int e = 0; e < NEXP; ++e) acc[e] = 0.f;
    for (int k = l; k < HD; k += 64) {
        const float xv = x[k];
#pragma unroll
        for (int e = 0; e < NEXP; ++e) acc[e] += xv * GW[e * HD + k];
    }
#pragma unroll
    for (int e = 0; e < NEXP; ++e) {
        float v = acc[e];
#pragma unroll
        for (int m = 32; m >= 1; m >>= 1) v += __shfl_xor(v, m, 64);
        acc[e] = v;
    }
    if (l == 0) {
        float s[NEXP], choice[NEXP];
#pragma unroll
        for (int e = 0; e < NEXP; ++e) {
            s[e] = 1.f / (1.f + __expf(-acc[e]));
            choice[e] = s[e] + bias[e];
        }
        int idx[TOPK]; float wv[TOPK]; float wsum = 0.f;
        bool used[NEXP];
#pragma unroll
        for (int e = 0; e < NEXP; ++e) used[e] = false;
        for (int j = 0; j < TOPK; ++j) {
            float best = -1e30f; int bi = 0;
            for (int e = 0; e < NEXP; ++e)
                if (!used[e] && choice[e] > best) { best = choice[e]; bi = e; }
            used[bi] = true; idx[j] = bi; wv[j] = s[bi]; wsum += s[bi];
        }
        const float scale = 2.5f / wsum;
        for (int j = 0; j < TOPK; ++j) {
            const int e = idx[j];
            const int pos = atomicAdd(&counts[e], 1);
            lists[e * T_TOK + pos] = t;
            wgts[e * T_TOK + pos] = wv[j] * scale;
        }
    }
}

__global__ void offsets_kernel(const int* __restrict__ counts, int* __restrict__ offs)
{
    if (threadIdx.x == 0 && blockIdx.x == 0) {
        int a = 0;
        for (int e = 0; e < NEXP; ++e) { offs[e] = a; a += counts[e]; }
    }
}

// ============== bf16 path: m97-style GEMMs with global_load_lds ==============
// Tile 128 x (64 gate + 64 up), BK=32, 4 waves (2x2). LDS unpadded (stride 32
// shorts = 64B/row) — required by global_load_lds lane-contiguous landing.
__global__ __launch_bounds__(256) void gateup_bf(
    const short* __restrict__ Xbf, const short* __restrict__ Wbf,
    const int* __restrict__ counts, const int* __restrict__ offs,
    const int* __restrict__ lists, short* __restrict__ Hout,
    int K, int Ih, int denseCount)
{
    __shared__ short sA[128][32];
    __shared__ short sB[128][32];
    const int e = blockIdx.z;
    const int cnt = counts ? counts[e] : denseCount;
    const int m0 = blockIdx.y * 128;
    if (m0 >= cnt) return;
    const int i0 = blockIdx.x * 64;
    const short* We = Wbf + (size_t)e * (2 * (size_t)Ih) * K;
    const int hbase = offs ? offs[e] : 0;

    const int tid = threadIdx.x;
    const int wave = tid >> 6, lane = tid & 63;
    // staging: wave w fills tile rows [w*32, w*32+32) in two wave-instrs of 16 rows
    const int srow0 = wave * 32 + (lane >> 2);
    const int srow1 = srow0 + 16;
    const int scol = (lane & 3) * 8;          // bf16 element col (16B per lane)

    int ar0 = m0 + srow0; if (ar0 > cnt - 1) ar0 = cnt - 1;
    int ar1 = m0 + srow1; if (ar1 > cnt - 1) ar1 = cnt - 1;
    const int tok0 = lists ? lists[e * T_TOK + ar0] : ar0;
    const int tok1 = lists ? lists[e * T_TOK + ar1] : ar1;
    const short* ag0 = Xbf + (size_t)tok0 * K + scol;
    const short* ag1 = Xbf + (size_t)tok1 * K + scol;
    const int br0 = (srow0 < 64) ? (i0 + srow0) : (Ih + i0 + srow0 - 64);
    const int br1 = (srow1 < 64) ? (i0 + srow1) : (Ih + i0 + srow1 - 64);
    const short* bg0 = We + (size_t)br0 * K + scol;
    const short* bg1 = We + (size_t)br1 * K + scol;
    short* la0 = &sA[wave * 32][0];
    short* la1 = &sA[wave * 32 + 16][0];
    short* lb0 = &sB[wave * 32][0];
    short* lb1 = &sB[wave * 32 + 16][0];

    const int wx = wave & 1, wy = wave >> 1;
    const int l15 = lane & 15, l4 = lane >> 4;

    floatx4 acc[4][4];
#pragma unroll
    for (int a = 0; a < 4; ++a)
#pragma unroll
        for (int b = 0; b < 4; ++b) acc[a][b] = (floatx4){0.f, 0.f, 0.f, 0.f};

    for (int k0 = 0; k0 < K; k0 += 32) {
        gload_lds16(ag0 + k0, la0);
        gload_lds16(ag1 + k0, la1);
        gload_lds16(bg0 + k0, lb0);
        gload_lds16(bg1 + k0, lb1);
        __syncthreads();   // drains vmcnt (global_load_lds) + barrier
        short8 af[4], bfr[4];
#pragma unroll
        for (int mc = 0; mc < 4; ++mc)
            af[mc] = *(const short8*)&sA[wy * 64 + mc * 16 + l15][l4 * 8];
#pragma unroll
        for (int cb = 0; cb < 4; ++cb) {
            const int br = ((cb < 2) ? 0 : 64) + wx * 32 + (cb & 1) * 16 + l15;
            bfr[cb] = *(const short8*)&sB[br][l4 * 8];
        }
#pragma unroll
        for (int mc = 0; mc < 4; ++mc)
#pragma unroll
            for (int cb = 0; cb < 4; ++cb)
                acc[mc][cb] = __builtin_amdgcn_mfma_f32_16x16x32_bf16(
                    af[mc], bfr[cb], acc[mc][cb], 0, 0, 0);
        __syncthreads();
    }

#pragma unroll
    for (int mc = 0; mc < 4; ++mc)
#pragma unroll
        for (int cb = 0; cb < 2; ++cb)
#pragma unroll
            for (int r = 0; r < 4; ++r) {
                const int mrel = wy * 64 + mc * 16 + l4 * 4 + r;
                if (m0 + mrel < cnt) {
                    const float g = acc[mc][cb][r];
                    const float u = acc[mc][cb + 2][r];
                    const float h = g / (1.f + __expf(-g)) * u;
                    const int col = i0 + wx * 32 + cb * 16 + l15;
                    Hout[(size_t)(hbase + m0 + mrel) * Ih + col] = f2bf(h);
                }
            }
}

__global__ __launch_bounds__(256) void down_bf(
    const short* __restrict__ Hin, const short* __restrict__ W2bf,
    const int* __restrict__ counts, const int* __restrict__ offs,
    const int* __restrict__ lists, const float* __restrict__ wgts,
    float* __restrict__ out, int Kih, int Ho, int denseCount)
{
    __shared__ short sA[128][32];
    __shared__ short sB[128][32];
    const int e = blockIdx.z;
    const int cnt = counts ? counts[e] : denseCount;
    const int m0 = blockIdx.y * 128;
    if (m0 >= cnt) return;
    const int n0 = blockIdx.x * 128;
    const short* W2e = W2bf + (size_t)e * (size_t)Ho * Kih;
    const int hbase = offs ? offs[e] : 0;

    const int tid = threadIdx.x;
    const int wave = tid >> 6, lane = tid & 63;
    const int srow0 = wave * 32 + (lane >> 2);
    const int srow1 = srow0 + 16;
    const int scol = (lane & 3) * 8;

    int ar0 = m0 + srow0; if (ar0 > cnt - 1) ar0 = cnt - 1;
    int ar1 = m0 + srow1; if (ar1 > cnt - 1) ar1 = cnt - 1;
    const short* ag0 = Hin + (size_t)(hbase + ar0) * Kih + scol;
    const short* ag1 = Hin + (size_t)(hbase + ar1) * Kih + scol;
    const short* bg0 = W2e + (size_t)(n0 + srow0) * Kih + scol;
    const short* bg1 = W2e + (size_t)(n0 + srow1) * Kih + scol;
    short* la0 = &sA[wave * 32][0];
    short* la1 = &sA[wave * 32 + 16][0];
    short* lb0 = &sB[wave * 32][0];
    short* lb1 = &sB[wave * 32 + 16][0];

    const int wx = wave & 1, wy = wave >> 1;
    const int l15 = lane & 15, l4 = lane >> 4;

    floatx4 acc[4][4];
#pragma unroll
    for (int a = 0; a < 4; ++a)
#pragma unroll
        for (int b = 0; b < 4; ++b) acc[a][b] = (floatx4){0.f, 0.f, 0.f, 0.f};

    for (int k0 = 0; k0 < Kih; k0 += 32) {
        gload_lds16(ag0 + k0, la0);
        gload_lds16(ag1 + k0, la1);
        gload_lds16(bg0 + k0, lb0);
        gload_lds16(bg1 + k0, lb1);
        __syncthreads();
        short8 af[4], bfr[4];
#pragma unroll
        for (int mc = 0; mc < 4; ++mc)
            af[mc] = *(const short8*)&sA[wy * 64 + mc * 16 + l15][l4 * 8];
#pragma unroll
        for (int cb = 0; cb < 4; ++cb)
            bfr[cb] = *(const short8*)&sB[wx * 64 + cb * 16 + l15][l4 * 8];
#pragma unroll
        for (int mc = 0; mc < 4; ++mc)
#pragma unroll
            for (int cb = 0; cb < 4; ++cb)
                acc[mc][cb] = __builtin_amdgcn_mfma_f32_16x16x32_bf16(
                    af[mc], bfr[cb], acc[mc][cb], 0, 0, 0);
        __syncthreads();
    }

#pragma unroll
    for (int mc = 0; mc < 4; ++mc)
#pragma unroll
        for (int r = 0; r < 4; ++r) {
            const int mrel = wy * 64 + mc * 16 + l4 * 4 + r;
            if (m0 + mrel >= cnt) continue;
            if (lists) {
                const int t = lists[e * T_TOK + m0 + mrel];
                const float w = wgts[e * T_TOK + m0 + mrel];
                float* orow = out + (size_t)t * Ho + n0 + wx * 64 + l15;
#pragma unroll
                for (int cb = 0; cb < 4; ++cb)
                    atomicAdd(orow + cb * 16, w * acc[mc][cb][r]);
            } else {
                float* orow = out + (size_t)(m0 + mrel) * Ho + n0 + wx * 64 + l15;
#pragma unroll
                for (int cb = 0; cb < 4; ++cb)
                    orow[cb * 16] = acc[mc][cb][r];
            }
        }
}

// ============== fp32 fallback path (round-1, proven) =========================
__global__ __launch_bounds__(256) void gateup_kernel(
    const float* __restrict__ X, const float* __restrict__ W,
    const int* __restrict__ counts, const int* __restrict__ offs,
    const int* __restrict__ lists, short* __restrict__ Hout,
    int K, int Ih, int denseCount)
{
    __shared__ short sA[128][40];
    __shared__ short sB[128][40];
    const int e = blockIdx.z;
    const int cnt = counts ? counts[e] : denseCount;
    const int m0 = blockIdx.y * 128;
    if (m0 >= cnt) return;
    const int i0 = blockIdx.x * 64;
    const float* We = W + (size_t)e * (size_t)(2 * Ih) * K;
    const int hbase = offs ? offs[e] : 0;

    const int tid = threadIdx.x;
    const int lrow = tid >> 1;
    const int kc = (tid & 1) * 16;

    int am = m0 + lrow; if (am > cnt - 1) am = cnt - 1;
    const int tok = lists ? lists[e * T_TOK + am] : am;
    const float* aptr = X + (size_t)tok * K + kc;
    const int brow = (lrow < 64) ? (i0 + lrow) : (Ih + i0 + (lrow - 64));
    const float* bptr = We + (size_t)brow * K + kc;

    const int wave = tid >> 6, lane = tid & 63;
    const int wx = wave & 1, wy = wave >> 1;
    const int l15 = lane & 15, l4 = lane >> 4;

    floatx4 acc[4][4];
#pragma unroll
    for (int a = 0; a < 4; ++a)
#pragma unroll
        for (int b = 0; b < 4; ++b) acc[a][b] = (floatx4){0.f, 0.f, 0.f, 0.f};

    for (int k0 = 0; k0 < K; k0 += 32) {
        const float4 a0 = *(const float4*)(aptr + k0);
        const float4 a1 = *(const float4*)(aptr + k0 + 4);
        const float4 a2 = *(const float4*)(aptr + k0 + 8);
        const float4 a3 = *(const float4*)(aptr + k0 + 12);
        const float4 b0 = *(const float4*)(bptr + k0);
        const float4 b1 = *(const float4*)(bptr + k0 + 4);
        const float4 b2 = *(const float4*)(bptr + k0 + 8);
        const float4 b3 = *(const float4*)(bptr + k0 + 12);
        *(short8*)&sA[lrow][kc]     = pack8(a0, a1);
        *(short8*)&sA[lrow][kc + 8] = pack8(a2, a3);
        *(short8*)&sB[lrow][kc]     = pack8(b0, b1);
        *(short8*)&sB[lrow][kc + 8] = pack8(b2, b3);
        __syncthreads();
        short8 af[4], bfr[4];
#pragma unroll
        for (int mc = 0; mc < 4; ++mc)
            af[mc] = *(const short8*)&sA[wy * 64 + mc * 16 + l15][l4 * 8];
#pragma unroll
        for (int cb = 0; cb < 4; ++cb) {
            const int br = ((cb < 2) ? 0 : 64) + wx * 32 + (cb & 1) * 16 + l15;
            bfr[cb] = *(const short8*)&sB[br][l4 * 8];
        }
#pragma unroll
        for (int mc = 0; mc < 4; ++mc)
#pragma unroll
            for (int cb = 0; cb < 4; ++cb)
                acc[mc][cb] = __builtin_amdgcn_mfma_f32_16x16x32_bf16(
                    af[mc], bfr[cb], acc[mc][cb], 0, 0, 0);
        __syncthreads();
    }

#pragma unroll
    for (int mc = 0; mc < 4; ++mc)
#pragma unroll
        for (int cb = 0; cb < 2; ++cb)
#pragma unroll
            for (int r = 0; r < 4; ++r) {
                const int mrel = wy * 64 + mc * 16 + l4 * 4 + r;
                if (m0 + mrel < cnt) {
                    const float g = acc[mc][cb][r];
                    const float u = acc[mc][cb + 2][r];
                    const float h = g / (1.f + __expf(-g)) * u;
                    const int col = i0 + wx * 32 + cb * 16 + l15;
                    Hout[(size_t)(hbase + m0 + mrel) * Ih + col] = f2bf(h);
                }
            }
}

__global__ __launch_bounds__(256) void down_kernel(
    const short* __restrict__ Hin, const float* __restrict__ W2,
    const int* __restrict__ counts, const int* __restrict__ offs,
    const int* __restrict__ lists, const float* __restrict__ wgts,
    float* __restrict__ out, int Kih, int Ho, int denseCount)
{
    __shared__ short sA[128][40];
    __shared__ short sB[128][40];
    const int e = blockIdx.z;
    const int cnt = counts ? counts[e] : denseCount;
    const int m0 = blockIdx.y * 128;
    if (m0 >= cnt) return;
    const int n0 = blockIdx.x * 128;
    const float* W2e = W2 + (size_t)e * (size_t)Ho * Kih;
    const int hbase = offs ? offs[e] : 0;

    const int tid = threadIdx.x;
    const int lrow = tid >> 1;
    const int kc = (tid & 1) * 16;

    int am = m0 + lrow; if (am > cnt - 1) am = cnt - 1;
    const short* aptr = Hin + (size_t)(hbase + am) * Kih + kc;
    const float* bptr = W2e + (size_t)(n0 + lrow) * Kih + kc;

    const int wave = tid >> 6, lane = tid & 63;
    const int wx = wave & 1, wy = wave >> 1;
    const int l15 = lane & 15, l4 = lane >> 4;

    floatx4 acc[4][4];
#pragma unroll
    for (int a = 0; a < 4; ++a)
#pragma unroll
        for (int b = 0; b < 4; ++b) acc[a][b] = (floatx4){0.f, 0.f, 0.f, 0.f};

    for (int k0 = 0; k0 < Kih; k0 += 32) {
        const short8 ha0 = *(const short8*)(aptr + k0);
        const short8 ha1 = *(const short8*)(aptr + k0 + 8);
        const float4 b0 = *(const float4*)(bptr + k0);
        const float4 b1 = *(const float4*)(bptr + k0 + 4);
        const float4 b2 = *(const float4*)(bptr + k0 + 8);
        const float4 b3 = *(const float4*)(bptr + k0 + 12);
        *(short8*)&sA[lrow][kc]     = ha0;
        *(short8*)&sA[lrow][kc + 8] = ha1;
        *(short8*)&sB[lrow][kc]     = pack8(b0, b1);
        *(short8*)&sB[lrow][kc + 8] = pack8(b2, b3);
        __syncthreads();
        short8 af[4], bfr[4];
#pragma unroll
        for (int mc = 0; mc < 4; ++mc)
            af[mc] = *(const short8*)&sA[wy * 64 + mc * 16 + l15][l4 * 8];
#pragma unroll
        for (int cb = 0; cb < 4; ++cb)
            bfr[cb] = *(const short8*)&sB[wx * 64 + cb * 16 + l15][l4 * 8];
#pragma unroll
        for (int mc = 0; mc < 4; ++mc)
#pragma unroll
            for (int cb = 0; cb < 4; ++cb)
                acc[mc][cb] = __builtin_amdgcn_mfma_f32_16x16x32_bf16(
                    af[mc], bfr[cb], acc[mc][cb], 0, 0, 0);
        __syncthreads();
    }

#pragma unroll
    for (int mc = 0; mc < 4; ++mc)
#pragma unroll
        for (int r = 0; r < 4; ++r) {
            const int mrel = wy * 64 + mc * 16 + l4 * 4 + r;
            if (m0 + mrel >= cnt) continue;
            if (lists) {
                const int t = lists[e * T_TOK + m0 + mrel];
                const float w = wgts[e * T_TOK + m0 + mrel];
                float* orow = out + (size_t)t * Ho + n0 + wx * 64 + l15;
#pragma unroll
                for (int cb = 0; cb < 4; ++cb)
                    atomicAdd(orow + cb * 16, w * acc[mc][cb][r]);
            } else {
                float* orow = out + (size_t)(m0 + mrel) * Ho + n0 + wx * 64 + l15;
#pragma unroll
                for (int cb = 0; cb < 4; ++cb)
                    orow[cb * 16] = acc[mc][cb][r];
            }
        }
}

extern "C" void kernel_launch(void* const* d_in, const int* in_sizes, int n_in,
                              void* d_out, int out_size, void* d_ws, size_t ws_size,
                              hipStream_t stream) {
    const float* X    = (const float*)d_in[0];  // [1024,2048]
    const float* GW   = (const float*)d_in[1];  // [16,2048]
    const float* BIAS = (const float*)d_in[2];  // [16]
    const float* W1   = (const float*)d_in[3];  // [16,2048,2048]
    const float* W2   = (const float*)d_in[4];  // [16,2048,1024]
    const float* SW1  = (const float*)d_in[5];  // [4096,2048]
    const float* SW2  = (const float*)d_in[6];  // [2048,2048]
    float* out = (float*)d_out;                 // [1024,2048] fp32

    char* ws = (char*)d_ws;
    int*   counts = (int*)ws;
    int*   offs   = counts + 16;
    int*   lists  = offs + 16;
    float* wgts   = (float*)(lists + 16 * 1024);
    short* h_r    = (short*)(ws + 135168);              // 6144*1024 bf16
    short* h_s    = (short*)(ws + 135168 + 12582912);   // 1024*2048 bf16
    const size_t BASE = 135168 + 12582912 + 4194304;    // 16,912,384

    // bf16 weight/activation cache regions
    short* Xbf   = (short*)(ws + BASE);                       //  4,194,304
    short* W1bf  = (short*)(ws + BASE + 4194304);             // 134,217,728
    short* W2bf  = (short*)(ws + BASE + 4194304 + 134217728); //  67,108,864
    short* SW1bf = (short*)(ws + BASE + 205520896);           //  16,777,216
    short* SW2bf = (short*)(ws + BASE + 222298112);           //   8,388,608
    const size_t WS_BF = BASE + 230686720;                    // ~236 MB

    if (ws_size < BASE) return;  // can't run at all

    hipMemsetAsync(counts, 0, 16 * sizeof(int), stream);
    router_kernel<<<T_TOK, 64, 0, stream>>>(X, GW, BIAS, counts, lists, wgts);
    offsets_kernel<<<1, 64, 0, stream>>>(counts, offs);

    if (ws_size >= WS_BF) {
        // ---- bf16 fast path ----
        cvt_kernel<<<2048, 256, 0, stream>>>(X,   Xbf,   2097152 / 4);
        cvt_kernel<<<2048, 256, 0, stream>>>(W1,  W1bf,  67108864 / 4);
        cvt_kernel<<<2048, 256, 0, stream>>>(W2,  W2bf,  33554432 / 4);
        cvt_kernel<<<2048, 256, 0, stream>>>(SW1, SW1bf, 8388608 / 4);
        cvt_kernel<<<2048, 256, 0, stream>>>(SW2, SW2bf, 4194304 / 4);

        gateup_bf<<<dim3(32, 8, 1), 256, 0, stream>>>(
            Xbf, SW1bf, nullptr, nullptr, nullptr, h_s, HD, 2048, T_TOK);
        gateup_bf<<<dim3(16, 8, NEXP), 256, 0, stream>>>(
            Xbf, W1bf, counts, offs, lists, h_r, HD, 1024, 0);

        down_bf<<<dim3(16, 8, 1), 256, 0, stream>>>(
            h_s, SW2bf, nullptr, nullptr, nullptr, nullptr, out, 2048, HD, T_TOK);
        down_bf<<<dim3(16, 8, NEXP), 256, 0, stream>>>(
            h_r, W2bf, counts, offs, lists, wgts, out, 1024, HD, 0);
    } else {
        // ---- fp32-staging fallback (round-1 path) ----
        gateup_kernel<<<dim3(32, 8, 1), 256, 0, stream>>>(
            X, SW1, nullptr, nullptr, nullptr, h_s, HD, 2048, T_TOK);
        gateup_kernel<<<dim3(16, 8, NEXP), 256, 0, stream>>>(
            X, W1, counts, offs, lists, h_r, HD, 1024, 0);

        down_kernel<<<dim3(16, 8, 1), 256, 0, stream>>>(
            h_s, SW2, nullptr, nullptr, nullptr, nullptr, out, 2048, HD, T_TOK);
        down_kernel<<<dim3(16, 8, NEXP), 256, 0, stream>>>(
            h_r, W2, counts, offs, lists, wgts, out, 1024, HD, 0);
    }
}

// Round 3
// 895.953 us; speedup vs baseline: 1.0889x; 1.0284x over previous
//
#include <hip/hip_runtime.h>
#include <hip/hip_bf16.h>

#define T_TOK 1024
#define NEXP 16
#define HD 2048
#define TOPK 6

typedef __attribute__((ext_vector_type(8))) short short8;
typedef __attribute__((ext_vector_type(4))) float floatx4;

__device__ __forceinline__ short f2bf(float f) {
    unsigned u = __builtin_bit_cast(unsigned, f);
    u += 0x7FFFu + ((u >> 16) & 1u);
    return (short)(u >> 16);
}

typedef __attribute__((address_space(1))) void gvoid;
typedef __attribute__((address_space(3))) void lvoid;
__device__ __forceinline__ void gload_lds16(const void* g, void* l) {
    __builtin_amdgcn_global_load_lds((gvoid*)g, (lvoid*)l, 16, 0, 0);
}

// ---------------- fp32 -> bf16 bulk convert, all 5 tensors in one launch -----
__global__ __launch_bounds__(256) void cvt_all(
    const float* __restrict__ X, const float* __restrict__ W1,
    const float* __restrict__ W2, const float* __restrict__ SW1,
    const float* __restrict__ SW2,
    short* __restrict__ Xb, short* __restrict__ W1b, short* __restrict__ W2b,
    short* __restrict__ SW1b, short* __restrict__ SW2b)
{
    const int C0 = 524288;          // X      [1024*2048]/4
    const int C1 = C0 + 16777216;   // W1     [16*2048*2048]/4
    const int C2 = C1 + 8388608;    // W2     [16*2048*1024]/4
    const int C3 = C2 + 2097152;    // SW1    [4096*2048]/4
    const int C4 = C3 + 1048576;    // SW2    [2048*2048]/4
    for (int i = blockIdx.x * blockDim.x + threadIdx.x; i < C4;
         i += gridDim.x * blockDim.x) {
        const float* s; short* d; int l;
        if (i < C0)      { s = X;   d = Xb;   l = i; }
        else if (i < C1) { s = W1;  d = W1b;  l = i - C0; }
        else if (i < C2) { s = W2;  d = W2b;  l = i - C1; }
        else if (i < C3) { s = SW1; d = SW1b; l = i - C2; }
        else             { s = SW2; d = SW2b; l = i - C3; }
        const float4 v = ((const float4*)s)[l];
        short4 o;
        o.x = f2bf(v.x); o.y = f2bf(v.y); o.z = f2bf(v.z); o.w = f2bf(v.w);
        ((short4*)d)[l] = o;
    }
}

// ---------------- router: fp32 logits -> sigmoid -> top6 -> lists + tables ---
__global__ __launch_bounds__(64) void router_kernel(
    const float* __restrict__ X, const float* __restrict__ GW,
    const float* __restrict__ bias, int* __restrict__ counts,
    int* __restrict__ lists, int* __restrict__ tok_e,
    int* __restrict__ tok_pos, float* __restrict__ tok_w)
{
    const int t = blockIdx.x;
    const int l = threadIdx.x;
    const float* x = X + (size_t)t * HD;
    float acc[NEXP];
#pragma unroll
    for (int e = 0; e < NEXP; ++e) acc[e] = 0.f;
    for (int k = l; k < HD; k += 64) {
        const float xv = x[k];
#pragma unroll
        for (int e = 0; e < NEXP; ++e) acc[e] += xv * GW[e * HD + k];
    }
#pragma unroll
    for (int e = 0; e < NEXP; ++e) {
        float v = acc[e];
#pragma unroll
        for (int m = 32; m >= 1; m >>= 1) v += __shfl_xor(v, m, 64);
        acc[e] = v;
    }
    if (l == 0) {
        float s[NEXP], choice[NEXP];
#pragma unroll
        for (int e = 0; e < NEXP; ++e) {
            s[e] = 1.f / (1.f + __expf(-acc[e]));
            choice[e] = s[e] + bias[e];
        }
        int idx[TOPK]; float wv[TOPK]; float wsum = 0.f;
        bool used[NEXP];
#pragma unroll
        for (int e = 0; e < NEXP; ++e) used[e] = false;
        for (int j = 0; j < TOPK; ++j) {
            float best = -1e30f; int bi = 0;
            for (int e = 0; e < NEXP; ++e)
                if (!used[e] && choice[e] > best) { best = choice[e]; bi = e; }
            used[bi] = true; idx[j] = bi; wv[j] = s[bi]; wsum += s[bi];
        }
        const float scale = 2.5f / wsum;
        for (int j = 0; j < TOPK; ++j) {
            const int e = idx[j];
            const int pos = atomicAdd(&counts[e], 1);
            lists[e * T_TOK + pos] = t;
            tok_e[t * TOPK + j] = e;
            tok_pos[t * TOPK + j] = pos;
            tok_w[t * TOPK + j] = wv[j] * scale;
        }
    }
}

__global__ void offsets_kernel(const int* __restrict__ counts, int* __restrict__ offs)
{
    if (threadIdx.x == 0 && blockIdx.x == 0) {
        int a = 0;
        for (int e = 0; e < NEXP; ++e) { offs[e] = a; a += counts[e]; }
    }
}

// ======= merged gate_up GEMM, double-buffered LDS, 1 barrier / K-step ========
// z in [0,16): routed expert z (Ih=1024, gathered). z==16: shared (Ih=2048, dense).
// Tile 128 x (64 gate + 64 up), BK=32, 4 waves (2x2).
__global__ __launch_bounds__(256) void gateup2(
    const short* __restrict__ Xbf, const short* __restrict__ W1bf,
    const short* __restrict__ SW1bf,
    const int* __restrict__ counts, const int* __restrict__ offs,
    const int* __restrict__ lists,
    short* __restrict__ h_r, short* __restrict__ h_s)
{
    __shared__ short sA[2][128][32];
    __shared__ short sB[2][128][32];
    const int z = blockIdx.z;
    const bool shx = (z == NEXP);
    if (!shx && blockIdx.x >= 16) return;
    const int cnt = shx ? T_TOK : counts[z];
    const int m0 = blockIdx.y * 128;
    if (m0 >= cnt) return;
    const int Ih = shx ? 2048 : 1024;
    const int i0 = blockIdx.x * 64;
    const short* W = shx ? SW1bf : (W1bf + (size_t)z * 2048 * HD);
    short* Hout = shx ? h_s : h_r;
    const int hbase = shx ? 0 : offs[z];

    const int tid = threadIdx.x;
    const int wave = tid >> 6, lane = tid & 63;
    const int srow0 = wave * 32 + (lane >> 2);   // 16 rows per wave-instr
    const int srow1 = srow0 + 16;
    const int scol = (lane & 3) * 8;             // 16B per lane

    int ar0 = m0 + srow0; if (ar0 > cnt - 1) ar0 = cnt - 1;
    int ar1 = m0 + srow1; if (ar1 > cnt - 1) ar1 = cnt - 1;
    const int tok0 = shx ? ar0 : lists[z * T_TOK + ar0];
    const int tok1 = shx ? ar1 : lists[z * T_TOK + ar1];
    const short* ag0 = Xbf + (size_t)tok0 * HD + scol;
    const short* ag1 = Xbf + (size_t)tok1 * HD + scol;
    const int br0 = (srow0 < 64) ? (i0 + srow0) : (Ih + i0 + srow0 - 64);
    const int br1 = (srow1 < 64) ? (i0 + srow1) : (Ih + i0 + srow1 - 64);
    const short* bg0 = W + (size_t)br0 * HD + scol;
    const short* bg1 = W + (size_t)br1 * HD + scol;

    const int wx = wave & 1, wy = wave >> 1;
    const int l15 = lane & 15, l4 = lane >> 4;

    floatx4 acc[4][4];
#pragma unroll
    for (int a = 0; a < 4; ++a)
#pragma unroll
        for (int b = 0; b < 4; ++b) acc[a][b] = (floatx4){0.f, 0.f, 0.f, 0.f};

    // prologue: stage k=0 into buf 0
    gload_lds16(ag0, &sA[0][wave * 32][0]);
    gload_lds16(ag1, &sA[0][wave * 32 + 16][0]);
    gload_lds16(bg0, &sB[0][wave * 32][0]);
    gload_lds16(bg1, &sB[0][wave * 32 + 16][0]);

    for (int k0 = 0; k0 < HD; k0 += 32) {
        const int p = (k0 >> 5) & 1;
        __syncthreads();   // drains vmcnt: buf p ready; prev reads of buf p^1 done
        if (k0 + 32 < HD) {
            const int q = p ^ 1;
            gload_lds16(ag0 + k0 + 32, &sA[q][wave * 32][0]);
            gload_lds16(ag1 + k0 + 32, &sA[q][wave * 32 + 16][0]);
            gload_lds16(bg0 + k0 + 32, &sB[q][wave * 32][0]);
            gload_lds16(bg1 + k0 + 32, &sB[q][wave * 32 + 16][0]);
        }
        short8 af[4], bfr[4];
#pragma unroll
        for (int mc = 0; mc < 4; ++mc)
            af[mc] = *(const short8*)&sA[p][wy * 64 + mc * 16 + l15][l4 * 8];
#pragma unroll
        for (int cb = 0; cb < 4; ++cb) {
            const int br = ((cb < 2) ? 0 : 64) + wx * 32 + (cb & 1) * 16 + l15;
            bfr[cb] = *(const short8*)&sB[p][br][l4 * 8];
        }
#pragma unroll
        for (int mc = 0; mc < 4; ++mc)
#pragma unroll
            for (int cb = 0; cb < 4; ++cb)
                acc[mc][cb] = __builtin_amdgcn_mfma_f32_16x16x32_bf16(
                    af[mc], bfr[cb], acc[mc][cb], 0, 0, 0);
    }

#pragma unroll
    for (int mc = 0; mc < 4; ++mc)
#pragma unroll
        for (int cb = 0; cb < 2; ++cb)
#pragma unroll
            for (int r = 0; r < 4; ++r) {
                const int mrel = wy * 64 + mc * 16 + l4 * 4 + r;
                if (m0 + mrel < cnt) {
                    const float g = acc[mc][cb][r];
                    const float u = acc[mc][cb + 2][r];
                    const float h = g / (1.f + __expf(-g)) * u;
                    const int col = i0 + wx * 32 + cb * 16 + l15;
                    Hout[(size_t)(hbase + m0 + mrel) * Ih + col] = f2bf(h);
                }
            }
}

// ======= merged down GEMM, double-buffered, dense stores (no atomics) ========
// z in [0,16): routed (Kih=1024, out rows = h2[hbase+m]). z==16: shared
// (Kih=2048, out rows = sh_out[m]). N=2048 both.
__global__ __launch_bounds__(256) void down2(
    const short* __restrict__ h_r, const short* __restrict__ h_s,
    const short* __restrict__ W2bf, const short* __restrict__ SW2bf,
    const int* __restrict__ counts, const int* __restrict__ offs,
    float* __restrict__ h2, float* __restrict__ sh_out)
{
    __shared__ short sA[2][128][32];
    __shared__ short sB[2][128][32];
    const int z = blockIdx.z;
    const bool shx = (z == NEXP);
    const int cnt = shx ? T_TOK : counts[z];
    const int m0 = blockIdx.y * 128;
    if (m0 >= cnt) return;
    const int Kih = shx ? 2048 : 1024;
    const int n0 = blockIdx.x * 128;
    const short* A = shx ? h_s : h_r;
    const short* W = shx ? SW2bf : (W2bf + (size_t)z * HD * 1024);
    float* outb = shx ? sh_out : h2;
    const int hbase = shx ? 0 : offs[z];

    const int tid = threadIdx.x;
    const int wave = tid >> 6, lane = tid & 63;
    const int srow0 = wave * 32 + (lane >> 2);
    const int srow1 = srow0 + 16;
    const int scol = (lane & 3) * 8;

    int ar0 = m0 + srow0; if (ar0 > cnt - 1) ar0 = cnt - 1;
    int ar1 = m0 + srow1; if (ar1 > cnt - 1) ar1 = cnt - 1;
    const short* ag0 = A + (size_t)(hbase + ar0) * Kih + scol;
    const short* ag1 = A + (size_t)(hbase + ar1) * Kih + scol;
    const short* bg0 = W + (size_t)(n0 + srow0) * Kih + scol;
    const short* bg1 = W + (size_t)(n0 + srow1) * Kih + scol;

    const int wx = wave & 1, wy = wave >> 1;
    const int l15 = lane & 15, l4 = lane >> 4;

    floatx4 acc[4][4];
#pragma unroll
    for (int a = 0; a < 4; ++a)
#pragma unroll
        for (int b = 0; b < 4; ++b) acc[a][b] = (floatx4){0.f, 0.f, 0.f, 0.f};

    gload_lds16(ag0, &sA[0][wave * 32][0]);
    gload_lds16(ag1, &sA[0][wave * 32 + 16][0]);
    gload_lds16(bg0, &sB[0][wave * 32][0]);
    gload_lds16(bg1, &sB[0][wave * 32 + 16][0]);

    for (int k0 = 0; k0 < Kih; k0 += 32) {
        const int p = (k0 >> 5) & 1;
        __syncthreads();
        if (k0 + 32 < Kih) {
            const int q = p ^ 1;
            gload_lds16(ag0 + k0 + 32, &sA[q][wave * 32][0]);
            gload_lds16(ag1 + k0 + 32, &sA[q][wave * 32 + 16][0]);
            gload_lds16(bg0 + k0 + 32, &sB[q][wave * 32][0]);
            gload_lds16(bg1 + k0 + 32, &sB[q][wave * 32 + 16][0]);
        }
        short8 af[4], bfr[4];
#pragma unroll
        for (int mc = 0; mc < 4; ++mc)
            af[mc] = *(const short8*)&sA[p][wy * 64 + mc * 16 + l15][l4 * 8];
#pragma unroll
        for (int cb = 0; cb < 4; ++cb)
            bfr[cb] = *(const short8*)&sB[p][wx * 64 + cb * 16 + l15][l4 * 8];
#pragma unroll
        for (int mc = 0; mc < 4; ++mc)
#pragma unroll
            for (int cb = 0; cb < 4; ++cb)
                acc[mc][cb] = __builtin_amdgcn_mfma_f32_16x16x32_bf16(
                    af[mc], bfr[cb], acc[mc][cb], 0, 0, 0);
    }

#pragma unroll
    for (int mc = 0; mc < 4; ++mc)
#pragma unroll
        for (int r = 0; r < 4; ++r) {
            const int mrel = wy * 64 + mc * 16 + l4 * 4 + r;
            if (m0 + mrel >= cnt) continue;
            float* orow = outb + (size_t)(hbase + m0 + mrel) * HD + n0 + wx * 64 + l15;
#pragma unroll
            for (int cb = 0; cb < 4; ++cb)
                orow[cb * 16] = acc[mc][cb][r];
        }
}

// ---------------- combine: out[t] = sh_out[t] + sum_j w_j * h2[row_j] --------
__global__ __launch_bounds__(256) void combine_kernel(
    const float* __restrict__ h2, const float* __restrict__ sh_out,
    const int* __restrict__ offs, const int* __restrict__ tok_e,
    const int* __restrict__ tok_pos, const float* __restrict__ tok_w,
    float* __restrict__ out)
{
    const int t = blockIdx.x;
    int rows[TOPK]; float w[TOPK];
#pragma unroll
    for (int j = 0; j < TOPK; ++j) {
        const int e = tok_e[t * TOPK + j];
        rows[j] = offs[e] + tok_pos[t * TOPK + j];
        w[j] = tok_w[t * TOPK + j];
    }
    for (int c = threadIdx.x * 4; c < HD; c += 256 * 4) {
        float4 acc = *(const float4*)(sh_out + (size_t)t * HD + c);
#pragma unroll
        for (int j = 0; j < TOPK; ++j) {
            const float4 v = *(const float4*)(h2 + (size_t)rows[j] * HD + c);
            acc.x += w[j] * v.x; acc.y += w[j] * v.y;
            acc.z += w[j] * v.z; acc.w += w[j] * v.w;
        }
        *(float4*)(out + (size_t)t * HD + c) = acc;
    }
}

extern "C" void kernel_launch(void* const* d_in, const int* in_sizes, int n_in,
                              void* d_out, int out_size, void* d_ws, size_t ws_size,
                              hipStream_t stream) {
    const float* X    = (const float*)d_in[0];  // [1024,2048]
    const float* GW   = (const float*)d_in[1];  // [16,2048]
    const float* BIAS = (const float*)d_in[2];  // [16]
    const float* W1   = (const float*)d_in[3];  // [16,2048,2048]
    const float* W2   = (const float*)d_in[4];  // [16,2048,1024]
    const float* SW1  = (const float*)d_in[5];  // [4096,2048]
    const float* SW2  = (const float*)d_in[6];  // [2048,2048]
    float* out = (float*)d_out;                 // [1024,2048] fp32

    char* ws = (char*)d_ws;
    int*   counts  = (int*)(ws + 0);            // 64 B
    int*   offs    = (int*)(ws + 64);           // 64 B
    int*   lists   = (int*)(ws + 256);          // 65536 B
    int*   tok_e   = (int*)(ws + 65792);        // 24576 B
    int*   tok_pos = (int*)(ws + 90368);        // 24576 B
    float* tok_w   = (float*)(ws + 114944);     // 24576 B
    short* h_r     = (short*)(ws + 262144);     // 6144*1024 bf16 = 12.6 MB
    short* h_s     = (short*)(ws + 12845056);   // 1024*2048 bf16 =  4.2 MB
    float* h2      = (float*)(ws + 17039360);   // 6144*2048 fp32 = 50.3 MB
    float* sh_out  = (float*)(ws + 67371008);   // 1024*2048 fp32 =  8.4 MB
    short* Xbf     = (short*)(ws + 75759616);   //  4.2 MB
    short* W1bf    = (short*)(ws + 79953920);   // 134.2 MB
    short* W2bf    = (short*)(ws + 214171648);  //  67.1 MB
    short* SW1bf   = (short*)(ws + 281280512);  //  16.8 MB
    short* SW2bf   = (short*)(ws + 298057728);  //   8.4 MB
    const size_t WS_NEEDED = 306446336;         // ~306 MB (ws is 1 GiB per profile)
    if (ws_size < WS_NEEDED) return;

    hipMemsetAsync(counts, 0, 64, stream);
    router_kernel<<<T_TOK, 64, 0, stream>>>(X, GW, BIAS, counts, lists,
                                            tok_e, tok_pos, tok_w);
    offsets_kernel<<<1, 64, 0, stream>>>(counts, offs);
    cvt_all<<<4096, 256, 0, stream>>>(X, W1, W2, SW1, SW2,
                                      Xbf, W1bf, W2bf, SW1bf, SW2bf);

    // gateup: z=0..15 routed (x<16 used), z=16 shared (x<32 used)
    gateup2<<<dim3(32, 8, NEXP + 1), 256, 0, stream>>>(
        Xbf, W1bf, SW1bf, counts, offs, lists, h_r, h_s);

    // down: z=0..15 routed -> h2, z=16 shared -> sh_out
    down2<<<dim3(16, 8, NEXP + 1), 256, 0, stream>>>(
        h_r, h_s, W2bf, SW2bf, counts, offs, h2, sh_out);

    combine_kernel<<<T_TOK, 256, 0, stream>>>(
        h2, sh_out, offs, tok_e, tok_pos, tok_w, out);
}

// Round 4
// 822.561 us; speedup vs baseline: 1.1861x; 1.0892x over previous
//
#include <hip/hip_runtime.h>
#include <hip/hip_bf16.h>

#define T_TOK 1024
#define NEXP 16
#define HD 2048
#define TOPK 6

typedef __attribute__((ext_vector_type(8))) short short8;
typedef __attribute__((ext_vector_type(4))) float floatx4;

__device__ __forceinline__ short f2bf(float f) {
    unsigned u = __builtin_bit_cast(unsigned, f);
    u += 0x7FFFu + ((u >> 16) & 1u);
    return (short)(u >> 16);
}

typedef __attribute__((address_space(1))) void gvoid;
typedef __attribute__((address_space(3))) void lvoid;
__device__ __forceinline__ void gload_lds16(const void* g, void* l) {
    __builtin_amdgcn_global_load_lds((gvoid*)g, (lvoid*)l, 16, 0, 0);
}

// s_waitcnt imm (gfx9): vmcnt[3:0|15:14], expcnt[6:4], lgkmcnt[11:8]
#define WAITCNT_VM4 0x0F74   // vmcnt(4), lgkm/exp no-wait
#define WAITCNT_VM0 0x0F70   // vmcnt(0)

// ---------------- fp32 -> bf16 bulk convert, all 5 tensors in one launch -----
__global__ __launch_bounds__(256) void cvt_all(
    const float* __restrict__ X, const float* __restrict__ W1,
    const float* __restrict__ W2, const float* __restrict__ SW1,
    const float* __restrict__ SW2,
    short* __restrict__ Xb, short* __restrict__ W1b, short* __restrict__ W2b,
    short* __restrict__ SW1b, short* __restrict__ SW2b)
{
    const int C0 = 524288;          // X      [1024*2048]/4
    const int C1 = C0 + 16777216;   // W1     [16*2048*2048]/4
    const int C2 = C1 + 8388608;    // W2     [16*2048*1024]/4
    const int C3 = C2 + 2097152;    // SW1    [4096*2048]/4
    const int C4 = C3 + 1048576;    // SW2    [2048*2048]/4
    for (int i = blockIdx.x * blockDim.x + threadIdx.x; i < C4;
         i += gridDim.x * blockDim.x) {
        const float* s; short* d; int l;
        if (i < C0)      { s = X;   d = Xb;   l = i; }
        else if (i < C1) { s = W1;  d = W1b;  l = i - C0; }
        else if (i < C2) { s = W2;  d = W2b;  l = i - C1; }
        else if (i < C3) { s = SW1; d = SW1b; l = i - C2; }
        else             { s = SW2; d = SW2b; l = i - C3; }
        const float4 v = ((const float4*)s)[l];
        short4 o;
        o.x = f2bf(v.x); o.y = f2bf(v.y); o.z = f2bf(v.z); o.w = f2bf(v.w);
        ((short4*)d)[l] = o;
    }
}

// ---------------- router: fp32 logits -> sigmoid -> top6 -> lists + tables ---
__global__ __launch_bounds__(64) void router_kernel(
    const float* __restrict__ X, const float* __restrict__ GW,
    const float* __restrict__ bias, int* __restrict__ counts,
    int* __restrict__ lists, int* __restrict__ tok_e,
    int* __restrict__ tok_pos, float* __restrict__ tok_w)
{
    const int t = blockIdx.x;
    const int l = threadIdx.x;
    const float* x = X + (size_t)t * HD;
    float acc[NEXP];
#pragma unroll
    for (int e = 0; e < NEXP; ++e) acc[e] = 0.f;
    for (int k = l; k < HD; k += 64) {
        const float xv = x[k];
#pragma unroll
        for (int e = 0; e < NEXP; ++e) acc[e] += xv * GW[e * HD + k];
    }
#pragma unroll
    for (int e = 0; e < NEXP; ++e) {
        float v = acc[e];
#pragma unroll
        for (int m = 32; m >= 1; m >>= 1) v += __shfl_xor(v, m, 64);
        acc[e] = v;
    }
    if (l == 0) {
        float s[NEXP], choice[NEXP];
#pragma unroll
        for (int e = 0; e < NEXP; ++e) {
            s[e] = 1.f / (1.f + __expf(-acc[e]));
            choice[e] = s[e] + bias[e];
        }
        int idx[TOPK]; float wv[TOPK]; float wsum = 0.f;
        bool used[NEXP];
#pragma unroll
        for (int e = 0; e < NEXP; ++e) used[e] = false;
        for (int j = 0; j < TOPK; ++j) {
            float best = -1e30f; int bi = 0;
            for (int e = 0; e < NEXP; ++e)
                if (!used[e] && choice[e] > best) { best = choice[e]; bi = e; }
            used[bi] = true; idx[j] = bi; wv[j] = s[bi]; wsum += s[bi];
        }
        const float scale = 2.5f / wsum;
        for (int j = 0; j < TOPK; ++j) {
            const int e = idx[j];
            const int pos = atomicAdd(&counts[e], 1);
            lists[e * T_TOK + pos] = t;
            tok_e[t * TOPK + j] = e;
            tok_pos[t * TOPK + j] = pos;
            tok_w[t * TOPK + j] = wv[j] * scale;
        }
    }
}

// ---------------- offsets + compacted tile descriptors -----------------------
// desc = (z<<16)|(y<<8)|x ; shared tiles (z=16) first, routed after.
__global__ __launch_bounds__(256) void offsets_descs(
    const int* __restrict__ counts, int* __restrict__ offs,
    int* __restrict__ gu, int* __restrict__ gu_n,
    int* __restrict__ dn, int* __restrict__ dn_n)
{
    __shared__ int base_gu[NEXP], base_dn[NEXP], nys[NEXP];
    if (threadIdx.x == 0) {
        int a = 0, bg = 256, bd = 128;
        for (int e = 0; e < NEXP; ++e) {
            offs[e] = a; a += counts[e];
            const int ny = (counts[e] + 127) >> 7;
            nys[e] = ny; base_gu[e] = bg; base_dn[e] = bd;
            bg += ny * 16; bd += ny * 16;
        }
        *gu_n = bg; *dn_n = bd;
    }
    __syncthreads();
    for (int i = threadIdx.x; i < 256; i += 256)
        gu[i] = (NEXP << 16) | ((i >> 5) << 8) | (i & 31);
    for (int i = threadIdx.x; i < 128; i += 256)
        dn[i] = (NEXP << 16) | ((i >> 4) << 8) | (i & 15);
    for (int e = 0; e < NEXP; ++e) {
        const int nt = nys[e] * 16;
        for (int i = threadIdx.x; i < nt; i += 256) {
            const int v = (e << 16) | ((i >> 4) << 8) | (i & 15);
            gu[base_gu[e] + i] = v;
            dn[base_dn[e] + i] = v;
        }
    }
}

// ======= gate_up GEMM: 3-buffer pipeline, raw barrier + vmcnt(4) =============
// z<16: routed expert (Ih=1024, gathered rows). z==16: shared (Ih=2048, dense).
// Tile 128 tokens x (64 gate + 64 up), BK=32, 4 waves (2x2).
// LDS K-chunk XOR swizzle: global chunk (lane&3)^((lane>>3)&3) lands at
// lane*16; frag col = (l4 ^ ((l15>>1)&3))*8 -> 2-way bank aliasing (free).
__global__ __launch_bounds__(256) void gateup3(
    const short* __restrict__ Xbf, const short* __restrict__ W1bf,
    const short* __restrict__ SW1bf,
    const int* __restrict__ counts, const int* __restrict__ offs,
    const int* __restrict__ lists, const int* __restrict__ descs,
    const int* __restrict__ ndesc,
    short* __restrict__ h_r, short* __restrict__ h_s)
{
    __shared__ short sA[3][128][32];
    __shared__ short sB[3][128][32];
    if ((int)blockIdx.x >= *ndesc) return;
    const int d = descs[blockIdx.x];
    const int z = d >> 16, yb = (d >> 8) & 255, xb = d & 255;
    const bool shx = (z == NEXP);
    const int cnt = shx ? T_TOK : counts[z];
    const int m0 = yb * 128;
    if (m0 >= cnt) return;
    const int Ih = shx ? 2048 : 1024;
    const int i0 = xb * 64;
    const short* W = shx ? SW1bf : (W1bf + (size_t)z * 2048 * HD);
    short* Hout = shx ? h_s : h_r;
    const int hbase = shx ? 0 : offs[z];

    const int tid = threadIdx.x;
    const int wave = tid >> 6, lane = tid & 63;
    const int srow0 = wave * 32 + (lane >> 2);   // 16 rows per wave-instr
    const int srow1 = srow0 + 16;
    const int scol = ((lane & 3) ^ ((lane >> 3) & 3)) * 8;  // swizzled 16B chunk

    int ar0 = m0 + srow0; if (ar0 > cnt - 1) ar0 = cnt - 1;
    int ar1 = m0 + srow1; if (ar1 > cnt - 1) ar1 = cnt - 1;
    const int tok0 = shx ? ar0 : lists[z * T_TOK + ar0];
    const int tok1 = shx ? ar1 : lists[z * T_TOK + ar1];
    const short* ag0 = Xbf + (size_t)tok0 * HD + scol;
    const short* ag1 = Xbf + (size_t)tok1 * HD + scol;
    const int br0 = (srow0 < 64) ? (i0 + srow0) : (Ih + i0 + srow0 - 64);
    const int br1 = (srow1 < 64) ? (i0 + srow1) : (Ih + i0 + srow1 - 64);
    const short* bg0 = W + (size_t)br0 * HD + scol;
    const short* bg1 = W + (size_t)br1 * HD + scol;

    const int wx = wave & 1, wy = wave >> 1;
    const int l15 = lane & 15, l4 = lane >> 4;
    const int fcol = (l4 ^ ((l15 >> 1) & 3)) * 8;   // swizzled frag read col

    floatx4 acc[4][4];
#pragma unroll
    for (int a = 0; a < 4; ++a)
#pragma unroll
        for (int b = 0; b < 4; ++b) acc[a][b] = (floatx4){0.f, 0.f, 0.f, 0.f};

    const int nsteps = HD / 32;   // 64
    // prologue: stage steps 0,1 into bufs 0,1
#pragma unroll
    for (int pb = 0; pb < 2; ++pb) {
        const int off = pb * 32;
        gload_lds16(ag0 + off, &sA[pb][wave * 32][0]);
        gload_lds16(ag1 + off, &sA[pb][wave * 32 + 16][0]);
        gload_lds16(bg0 + off, &sB[pb][wave * 32][0]);
        gload_lds16(bg1 + off, &sB[pb][wave * 32 + 16][0]);
    }

    int p = 0, q = 2;   // p = buf for step s; q = buf to stage (step s+2)
    for (int s = 0; s < nsteps; ++s) {
        // wait for this step's 4 loads (issued 2 steps ago); keep newer in flight
        if (s + 1 < nsteps) __builtin_amdgcn_s_waitcnt(WAITCNT_VM4);
        else                __builtin_amdgcn_s_waitcnt(WAITCNT_VM0);
        __builtin_amdgcn_s_barrier();
        if (s + 2 < nsteps) {
            const int off = (s + 2) * 32;
            gload_lds16(ag0 + off, &sA[q][wave * 32][0]);
            gload_lds16(ag1 + off, &sA[q][wave * 32 + 16][0]);
            gload_lds16(bg0 + off, &sB[q][wave * 32][0]);
            gload_lds16(bg1 + off, &sB[q][wave * 32 + 16][0]);
        }
        short8 af[4], bfr[4];
#pragma unroll
        for (int mc = 0; mc < 4; ++mc)
            af[mc] = *(const short8*)&sA[p][wy * 64 + mc * 16 + l15][fcol];
#pragma unroll
        for (int cb = 0; cb < 4; ++cb) {
            const int br = ((cb < 2) ? 0 : 64) + wx * 32 + (cb & 1) * 16 + l15;
            bfr[cb] = *(const short8*)&sB[p][br][fcol];
        }
#pragma unroll
        for (int mc = 0; mc < 4; ++mc)
#pragma unroll
            for (int cb = 0; cb < 4; ++cb)
                acc[mc][cb] = __builtin_amdgcn_mfma_f32_16x16x32_bf16(
                    af[mc], bfr[cb], acc[mc][cb], 0, 0, 0);
        p = (p == 2) ? 0 : p + 1;
        q = (q == 2) ? 0 : q + 1;
    }

#pragma unroll
    for (int mc = 0; mc < 4; ++mc)
#pragma unroll
        for (int cb = 0; cb < 2; ++cb)
#pragma unroll
            for (int r = 0; r < 4; ++r) {
                const int mrel = wy * 64 + mc * 16 + l4 * 4 + r;
                if (m0 + mrel < cnt) {
                    const float g = acc[mc][cb][r];
                    const float u = acc[mc][cb + 2][r];
                    const float h = g / (1.f + __expf(-g)) * u;
                    const int col = i0 + wx * 32 + cb * 16 + l15;
                    Hout[(size_t)(hbase + m0 + mrel) * Ih + col] = f2bf(h);
                }
            }
}

// ======= down GEMM: same pipeline, dense stores (no atomics) =================
__global__ __launch_bounds__(256) void down3(
    const short* __restrict__ h_r, const short* __restrict__ h_s,
    const short* __restrict__ W2bf, const short* __restrict__ SW2bf,
    const int* __restrict__ counts, const int* __restrict__ offs,
    const int* __restrict__ descs, const int* __restrict__ ndesc,
    float* __restrict__ h2, float* __restrict__ sh_out)
{
    __shared__ short sA[3][128][32];
    __shared__ short sB[3][128][32];
    if ((int)blockIdx.x >= *ndesc) return;
    const int d = descs[blockIdx.x];
    const int z = d >> 16, yb = (d >> 8) & 255, xb = d & 255;
    const bool shx = (z == NEXP);
    const int cnt = shx ? T_TOK : counts[z];
    const int m0 = yb * 128;
    if (m0 >= cnt) return;
    const int Kih = shx ? 2048 : 1024;
    const int n0 = xb * 128;
    const short* A = shx ? h_s : h_r;
    const short* W = shx ? SW2bf : (W2bf + (size_t)z * HD * 1024);
    float* outb = shx ? sh_out : h2;
    const int hbase = shx ? 0 : offs[z];

    const int tid = threadIdx.x;
    const int wave = tid >> 6, lane = tid & 63;
    const int srow0 = wave * 32 + (lane >> 2);
    const int srow1 = srow0 + 16;
    const int scol = ((lane & 3) ^ ((lane >> 3) & 3)) * 8;

    int ar0 = m0 + srow0; if (ar0 > cnt - 1) ar0 = cnt - 1;
    int ar1 = m0 + srow1; if (ar1 > cnt - 1) ar1 = cnt - 1;
    const short* ag0 = A + (size_t)(hbase + ar0) * Kih + scol;
    const short* ag1 = A + (size_t)(hbase + ar1) * Kih + scol;
    const short* bg0 = W + (size_t)(n0 + srow0) * Kih + scol;
    const short* bg1 = W + (size_t)(n0 + srow1) * Kih + scol;

    const int wx = wave & 1, wy = wave >> 1;
    const int l15 = lane & 15, l4 = lane >> 4;
    const int fcol = (l4 ^ ((l15 >> 1) & 3)) * 8;

    floatx4 acc[4][4];
#pragma unroll
    for (int a = 0; a < 4; ++a)
#pragma unroll
        for (int b = 0; b < 4; ++b) acc[a][b] = (floatx4){0.f, 0.f, 0.f, 0.f};

    const int nsteps = Kih / 32;   // 32 or 64
#pragma unroll
    for (int pb = 0; pb < 2; ++pb) {
        const int off = pb * 32;
        gload_lds16(ag0 + off, &sA[pb][wave * 32][0]);
        gload_lds16(ag1 + off, &sA[pb][wave * 32 + 16][0]);
        gload_lds16(bg0 + off, &sB[pb][wave * 32][0]);
        gload_lds16(bg1 + off, &sB[pb][wave * 32 + 16][0]);
    }

    int p = 0, q = 2;
    for (int s = 0; s < nsteps; ++s) {
        if (s + 1 < nsteps) __builtin_amdgcn_s_waitcnt(WAITCNT_VM4);
        else                __builtin_amdgcn_s_waitcnt(WAITCNT_VM0);
        __builtin_amdgcn_s_barrier();
        if (s + 2 < nsteps) {
            const int off = (s + 2) * 32;
            gload_lds16(ag0 + off, &sA[q][wave * 32][0]);
            gload_lds16(ag1 + off, &sA[q][wave * 32 + 16][0]);
            gload_lds16(bg0 + off, &sB[q][wave * 32][0]);
            gload_lds16(bg1 + off, &sB[q][wave * 32 + 16][0]);
        }
        short8 af[4], bfr[4];
#pragma unroll
        for (int mc = 0; mc < 4; ++mc)
            af[mc] = *(const short8*)&sA[p][wy * 64 + mc * 16 + l15][fcol];
#pragma unroll
        for (int cb = 0; cb < 4; ++cb)
            bfr[cb] = *(const short8*)&sB[p][wx * 64 + cb * 16 + l15][fcol];
#pragma unroll
        for (int mc = 0; mc < 4; ++mc)
#pragma unroll
            for (int cb = 0; cb < 4; ++cb)
                acc[mc][cb] = __builtin_amdgcn_mfma_f32_16x16x32_bf16(
                    af[mc], bfr[cb], acc[mc][cb], 0, 0, 0);
        p = (p == 2) ? 0 : p + 1;
        q = (q == 2) ? 0 : q + 1;
    }

#pragma unroll
    for (int mc = 0; mc < 4; ++mc)
#pragma unroll
        for (int r = 0; r < 4; ++r) {
            const int mrel = wy * 64 + mc * 16 + l4 * 4 + r;
            if (m0 + mrel >= cnt) continue;
            float* orow = outb + (size_t)(hbase + m0 + mrel) * HD + n0 + wx * 64 + l15;
#pragma unroll
            for (int cb = 0; cb < 4; ++cb)
                orow[cb * 16] = acc[mc][cb][r];
        }
}

// ---------------- combine: out[t] = sh_out[t] + sum_j w_j * h2[row_j] --------
__global__ __launch_bounds__(256) void combine_kernel(
    const float* __restrict__ h2, const float* __restrict__ sh_out,
    const int* __restrict__ offs, const int* __restrict__ tok_e,
    const int* __restrict__ tok_pos, const float* __restrict__ tok_w,
    float* __restrict__ out)
{
    const int t = blockIdx.x;
    int rows[TOPK]; float w[TOPK];
#pragma unroll
    for (int j = 0; j < TOPK; ++j) {
        const int e = tok_e[t * TOPK + j];
        rows[j] = offs[e] + tok_pos[t * TOPK + j];
        w[j] = tok_w[t * TOPK + j];
    }
    for (int c = threadIdx.x * 4; c < HD; c += 256 * 4) {
        float4 acc = *(const float4*)(sh_out + (size_t)t * HD + c);
#pragma unroll
        for (int j = 0; j < TOPK; ++j) {
            const float4 v = *(const float4*)(h2 + (size_t)rows[j] * HD + c);
            acc.x += w[j] * v.x; acc.y += w[j] * v.y;
            acc.z += w[j] * v.z; acc.w += w[j] * v.w;
        }
        *(float4*)(out + (size_t)t * HD + c) = acc;
    }
}

extern "C" void kernel_launch(void* const* d_in, const int* in_sizes, int n_in,
                              void* d_out, int out_size, void* d_ws, size_t ws_size,
                              hipStream_t stream) {
    const float* X    = (const float*)d_in[0];  // [1024,2048]
    const float* GW   = (const float*)d_in[1];  // [16,2048]
    const float* BIAS = (const float*)d_in[2];  // [16]
    const float* W1   = (const float*)d_in[3];  // [16,2048,2048]
    const float* W2   = (const float*)d_in[4];  // [16,2048,1024]
    const float* SW1  = (const float*)d_in[5];  // [4096,2048]
    const float* SW2  = (const float*)d_in[6];  // [2048,2048]
    float* out = (float*)d_out;                 // [1024,2048] fp32

    char* ws = (char*)d_ws;
    int*   counts  = (int*)(ws + 0);            // 64 B
    int*   offs    = (int*)(ws + 64);           // 64 B
    int*   lists   = (int*)(ws + 256);          // 65536 B
    int*   tok_e   = (int*)(ws + 65792);        // 24576 B
    int*   tok_pos = (int*)(ws + 90368);        // 24576 B
    float* tok_w   = (float*)(ws + 114944);     // 24576 B -> ends 139520
    int*   gu_n    = (int*)(ws + 139776);
    int*   dn_n    = (int*)(ws + 139780);
    int*   gu_desc = (int*)(ws + 139840);       // <=1280 ints
    int*   dn_desc = (int*)(ws + 145024);       // <=1152 ints -> ends ~149632
    short* h_r     = (short*)(ws + 262144);     // 6144*1024 bf16 = 12.6 MB
    short* h_s     = (short*)(ws + 12845056);   // 1024*2048 bf16 =  4.2 MB
    float* h2      = (float*)(ws + 17039360);   // 6144*2048 fp32 = 50.3 MB
    float* sh_out  = (float*)(ws + 67371008);   // 1024*2048 fp32 =  8.4 MB
    short* Xbf     = (short*)(ws + 75759616);   //  4.2 MB
    short* W1bf    = (short*)(ws + 79953920);   // 134.2 MB
    short* W2bf    = (short*)(ws + 214171648);  //  67.1 MB
    short* SW1bf   = (short*)(ws + 281280512);  //  16.8 MB
    short* SW2bf   = (short*)(ws + 298057728);  //   8.4 MB
    const size_t WS_NEEDED = 306446336;         // ~306 MB (ws is 1 GiB)
    if (ws_size < WS_NEEDED) return;

    hipMemsetAsync(counts, 0, 64, stream);
    router_kernel<<<T_TOK, 64, 0, stream>>>(X, GW, BIAS, counts, lists,
                                            tok_e, tok_pos, tok_w);
    offsets_descs<<<1, 256, 0, stream>>>(counts, offs, gu_desc, gu_n,
                                         dn_desc, dn_n);
    cvt_all<<<4096, 256, 0, stream>>>(X, W1, W2, SW1, SW2,
                                      Xbf, W1bf, W2bf, SW1bf, SW2bf);

    // static max grids; tail blocks read ndesc and exit
    gateup3<<<1280, 256, 0, stream>>>(Xbf, W1bf, SW1bf, counts, offs, lists,
                                      gu_desc, gu_n, h_r, h_s);
    down3<<<1152, 256, 0, stream>>>(h_r, h_s, W2bf, SW2bf, counts, offs,
                                    dn_desc, dn_n, h2, sh_out);
    combine_kernel<<<T_TOK, 256, 0, stream>>>(
        h2, sh_out, offs, tok_e, tok_pos, tok_w, out);
}